// Round 10
// baseline (820.836 us; speedup 1.0000x reference)
//
#include <hip/hip_runtime.h>
#include <hip/hip_cooperative_groups.h>

namespace cg = cooperative_groups;

#define N_NODES 50000
#define N_PAD   50048   // 782 * 64
#define N_EDGES 800000
#define N_GRAPHS 512
#define F_IN 96
#define HID 128
#define NBUCK 196       // buckets of 256 nodes (dst >> 8)
#define NCHUNK 512      // edge chunks
#define CHUNKE 1563     // ceil(800000/512)
#define NB_G 782        // gemm virtual blocks (N_PAD/64)
#define NB_AG 12500     // aggregate virtual blocks (N_NODES/4)

typedef __bf16 bf16x8 __attribute__((ext_vector_type(8)));
typedef float  f32x4  __attribute__((ext_vector_type(4)));

__device__ __forceinline__ unsigned short f2bf(float f) {
    union { float f; unsigned u; } v; v.f = f;
    unsigned r = v.u + 0x7FFFu + ((v.u >> 16) & 1u);  // RNE
    return (unsigned short)(r >> 16);
}
__device__ __forceinline__ float bflo(unsigned u) {
    union { unsigned u; float f; } v; v.u = u << 16; return v.f;
}
__device__ __forceinline__ float bfhi(unsigned u) {
    union { unsigned u; float f; } v; v.u = u & 0xFFFF0000u; return v.f;
}

// W f32 [K x 128] -> bf16 B-fragments: frag idx=(t*KS+s)*64+lane;
// element j: B[k=s*32+(lane>>4)*8+j][n=t*16+(lane&15)]
__device__ __forceinline__ void prep_one(const float* __restrict__ W, int KS, int idx,
                                         unsigned short* __restrict__ Wf) {
    int t = idx / (KS * 64);
    int rem = idx % (KS * 64);
    int s = rem / 64;
    int l = rem & 63;
    int n = t * 16 + (l & 15);
    int k0 = s * 32 + (l >> 4) * 8;
    unsigned short v[8];
#pragma unroll
    for (int j = 0; j < 8; ++j) v[j] = f2bf(W[(long)(k0 + j) * 128 + n]);
    uint4 o;
    o.x = (unsigned)v[0] | ((unsigned)v[1] << 16);
    o.y = (unsigned)v[2] | ((unsigned)v[3] << 16);
    o.z = (unsigned)v[4] | ((unsigned)v[5] << 16);
    o.w = (unsigned)v[6] | ((unsigned)v[7] << 16);
    *(uint4*)(Wf + (long)idx * 8) = o;
}

// ---- P0: per-chunk bucket histograms + weight prep ----
__device__ __forceinline__ void ph_hist(int bid, int tid, int nblk, const int* __restrict__ dst,
                                        const float* __restrict__ W1, const float* __restrict__ W2,
                                        unsigned short* __restrict__ W1f, unsigned short* __restrict__ W2f,
                                        int* __restrict__ bh, int* sm) {
    for (int v = bid; v < NCHUNK + 14; v += nblk) {
        if (v < NCHUNK) {
            for (int i = tid; i < NBUCK; i += 256) sm[i] = 0;
            __syncthreads();
            int e0 = v * CHUNKE, e1 = min(e0 + CHUNKE, N_EDGES);
            for (int e = e0 + tid; e < e1; e += 256)
                atomicAdd(&sm[dst[e] >> 8], 1);
            __syncthreads();
            for (int i = tid; i < NBUCK; i += 256) bh[v * NBUCK + i] = sm[i];
            __syncthreads();
        } else {
            int b = v - NCHUNK;
            if (b < 6) { int idx = b * 256 + tid; if (idx < 8 * 3 * 64) prep_one(W1, 3, idx, W1f); }
            else { int idx = (b - 6) * 256 + tid; if (idx < 8 * 4 * 64) prep_one(W2, 4, idx, W2f); }
        }
    }
}

// ---- P1: bucket totals ----
__device__ __forceinline__ void ph_totals(int bid, int tid, int nblk, const int* __restrict__ bh,
                                          int* __restrict__ total, int* sm) {
    for (int b = bid; b < NBUCK; b += nblk) {
        int ssum = 0;
        for (int c = tid; c < NCHUNK; c += 256) ssum += bh[c * NBUCK + b];
        sm[tid] = ssum;
        __syncthreads();
        for (int off = 128; off > 0; off >>= 1) {
            if (tid < off) sm[tid] += sm[tid + off];
            __syncthreads();
        }
        if (tid == 0) total[b] = sm[0];
        __syncthreads();
    }
}

// ---- P2: bstart (scan of totals) + per-(chunk,bucket) offsets ----
__device__ __forceinline__ void ph_goff(int bid, int tid, int nblk, const int* __restrict__ bh,
                                        const int* __restrict__ total, int* __restrict__ bstart,
                                        int* __restrict__ goff, int* sm) {
    int* st = sm;        // scanned totals (inclusive), computed once, kept
    int* s2 = sm + 256;  // per-bucket pair scan
    int tv = (tid < NBUCK) ? total[tid] : 0;
    st[tid] = tv;
    __syncthreads();
    for (int off = 1; off < 256; off <<= 1) {
        int t = 0;
        if (tid >= off) t = st[tid - off];
        __syncthreads();
        if (tid >= off) st[tid] += t;
        __syncthreads();
    }
    for (int b = bid; b < NBUCK; b += nblk) {
        int bs = st[b] - total[b];  // exclusive prefix for bucket b
        int a0 = bh[(2 * tid) * NBUCK + b];
        int a1 = bh[(2 * tid + 1) * NBUCK + b];
        s2[tid] = a0 + a1;
        __syncthreads();
        for (int off = 1; off < 256; off <<= 1) {
            int t = 0;
            if (tid >= off) t = s2[tid - off];
            __syncthreads();
            if (tid >= off) s2[tid] += t;
            __syncthreads();
        }
        int pex = s2[tid] - (a0 + a1);
        goff[(2 * tid) * NBUCK + b] = bs + pex;
        goff[(2 * tid + 1) * NBUCK + b] = bs + pex + a0;
        if (tid == 0) bstart[b] = bs;
        __syncthreads();
    }
    if (bid == 0 && tid == 0) bstart[NBUCK] = N_EDGES;
}

// ---- P3: scatter pairs bucket-grouped (LDS atomics only) ----
__device__ __forceinline__ void ph_scatter(int bid, int tid, int nblk, const int* __restrict__ src,
                                           const int* __restrict__ dst, const int* __restrict__ goff,
                                           uint2* __restrict__ ebuf, int* sm) {
    int* lg = sm;
    int* lc = sm + 256;
    for (int c = bid; c < NCHUNK; c += nblk) {
        for (int i = tid; i < NBUCK; i += 256) { lg[i] = goff[c * NBUCK + i]; lc[i] = 0; }
        __syncthreads();
        int e0 = c * CHUNKE, e1 = min(e0 + CHUNKE, N_EDGES);
        for (int e = e0 + tid; e < e1; e += 256) {
            int d = dst[e];
            int b = d >> 8;
            int slot = atomicAdd(&lc[b], 1);
            ebuf[lg[b] + slot] = make_uint2((unsigned)src[e], (unsigned)d);
        }
        __syncthreads();
    }
}

// ---- bucket_sort body (one bucket) ----
__device__ __forceinline__ void bsort_body(int b, int tid, const uint2* __restrict__ ebuf,
                                           const int* __restrict__ bstart, int* __restrict__ rowstart,
                                           int* __restrict__ cnt, float* __restrict__ dinv,
                                           int* __restrict__ esrc, int* sm) {
    int* lcnt = sm;
    int* ssc = sm + 256;
    int* ncur = sm + 512;
    int nbase = b * 256;
    int r0 = bstart[b], r1 = bstart[b + 1];
    lcnt[tid] = 0;
    __syncthreads();
    for (int i = r0 + tid; i < r1; i += 256)
        atomicAdd(&lcnt[(int)ebuf[i].y - nbase], 1);
    __syncthreads();
    int c = lcnt[tid];
    ssc[tid] = c;
    __syncthreads();
    for (int off = 1; off < 256; off <<= 1) {
        int t = 0;
        if (tid >= off) t = ssc[tid - off];
        __syncthreads();
        if (tid >= off) ssc[tid] += t;
        __syncthreads();
    }
    int rs = r0 + ssc[tid] - c;
    ncur[tid] = rs;
    int node = nbase + tid;
    if (node < N_NODES) {
        rowstart[node] = rs;
        cnt[node] = c;
        dinv[node] = rsqrtf((float)c + 1.0f);
    }
    __syncthreads();
    for (int i = r0 + tid; i < r1; i += 256) {
        uint2 p = ebuf[i];
        int pos = atomicAdd(&ncur[(int)p.y - nbase], 1);
        esrc[pos] = (int)p.x;
    }
    __syncthreads();
}

// ---- GEMM layer 1: raw = x(f32, cvt in-reg) @ W1 (dinv folded into aggregate) ----
__device__ __forceinline__ void gemm1_body(int vb, int tid, const float* __restrict__ A,
                                           const unsigned short* __restrict__ Wf,
                                           unsigned short* __restrict__ hp) {
    const int KS = 3;
    const int wave = tid >> 6, lane = tid & 63;
    const int r0 = vb * 64 + wave * 16;
    f32x4 acc[8];
#pragma unroll
    for (int t = 0; t < 8; ++t) acc[t] = (f32x4){0.f, 0.f, 0.f, 0.f};
    int arow = r0 + (lane & 15);
    if (arow >= N_NODES) arow = N_NODES - 1;
    const int kq = (lane >> 4) * 8;
    for (int s = 0; s < KS; ++s) {
        const float* ap = A + (long)arow * F_IN + s * 32 + kq;
        float4 a0 = *(const float4*)(ap);
        float4 a1 = *(const float4*)(ap + 4);
        union { uint4 u; bf16x8 b; } af;
        af.u.x = (unsigned)f2bf(a0.x) | ((unsigned)f2bf(a0.y) << 16);
        af.u.y = (unsigned)f2bf(a0.z) | ((unsigned)f2bf(a0.w) << 16);
        af.u.z = (unsigned)f2bf(a1.x) | ((unsigned)f2bf(a1.y) << 16);
        af.u.w = (unsigned)f2bf(a1.z) | ((unsigned)f2bf(a1.w) << 16);
#pragma unroll
        for (int t = 0; t < 8; ++t) {
            union { uint4 u; bf16x8 b; } bfr;
            bfr.u = *(const uint4*)(Wf + ((long)(t * KS + s) * 64 + lane) * 8);
            acc[t] = __builtin_amdgcn_mfma_f32_16x16x32_bf16(af.b, bfr.b, acc[t], 0, 0, 0);
        }
    }
    const int q = lane >> 4;
#pragma unroll
    for (int t = 0; t < 8; ++t) {
        int col = t * 16 + (lane & 15);
#pragma unroll
        for (int r = 0; r < 4; ++r) {
            int row = r0 + q * 4 + r;
            if (row < N_NODES) hp[(long)row * 128 + col] = f2bf(acc[t][r]);
        }
    }
}

// ---- GEMM layer 2: raw = h(bf16) @ W2 ----
__device__ __forceinline__ void gemm2_body(int vb, int tid, const unsigned short* __restrict__ A,
                                           const unsigned short* __restrict__ Wf,
                                           unsigned short* __restrict__ hp) {
    const int KS = 4;
    const int wave = tid >> 6, lane = tid & 63;
    const int r0 = vb * 64 + wave * 16;
    f32x4 acc[8];
#pragma unroll
    for (int t = 0; t < 8; ++t) acc[t] = (f32x4){0.f, 0.f, 0.f, 0.f};
    const int arow = r0 + (lane & 15);  // pad-row reads: finite poison, discarded on store
    const int kq = (lane >> 4) * 8;
    for (int s = 0; s < KS; ++s) {
        union { uint4 u; bf16x8 b; } af;
        af.u = *(const uint4*)(A + (long)arow * HID + s * 32 + kq);
#pragma unroll
        for (int t = 0; t < 8; ++t) {
            union { uint4 u; bf16x8 b; } bfr;
            bfr.u = *(const uint4*)(Wf + ((long)(t * KS + s) * 64 + lane) * 8);
            acc[t] = __builtin_amdgcn_mfma_f32_16x16x32_bf16(af.b, bfr.b, acc[t], 0, 0, 0);
        }
    }
    const int q = lane >> 4;
#pragma unroll
    for (int t = 0; t < 8; ++t) {
        int col = t * 16 + (lane & 15);
#pragma unroll
        for (int r = 0; r < 4; ++r) {
            int row = r0 + q * 4 + r;
            if (row < N_NODES) hp[(long)row * 128 + col] = f2bf(acc[t][r]);
        }
    }
}

// ---- aggregate: wave/node; hout[d] = relu(d_d*(sum_s d_s*raw_s + d_d*raw_d) + b) ----
__device__ __forceinline__ void aggregate_body(int vb, int tid, const uint4* __restrict__ hp4,
                                               const int* __restrict__ esrc,
                                               const int* __restrict__ rowstart,
                                               const int* __restrict__ cnt,
                                               const float* __restrict__ dinv,
                                               const float* __restrict__ bias,
                                               uint4* __restrict__ hout4) {
    int node = vb * 4 + (tid >> 6);
    if (node >= N_NODES) return;
    int lane = tid & 63;
    int eslot = lane >> 4;
    int ug = lane & 15;
    int start = rowstart[node];
    int end = start + cnt[node];

    float a[8];
#pragma unroll
    for (int k = 0; k < 8; ++k) a[k] = 0.f;

    for (int j = start; j < end; j += 16) {
        int e[4];
        uint4 v[4];
        float w[4];
#pragma unroll
        for (int q = 0; q < 4; ++q) {
            e[q] = j + q * 4 + eslot;
            int s = esrc[min(e[q], end - 1)];
            v[q] = hp4[(long)s * 16 + ug];
            w[q] = dinv[s];
        }
#pragma unroll
        for (int q = 0; q < 4; ++q) {
            if (e[q] < end) {
                a[0] += w[q] * bflo(v[q].x); a[1] += w[q] * bfhi(v[q].x);
                a[2] += w[q] * bflo(v[q].y); a[3] += w[q] * bfhi(v[q].y);
                a[4] += w[q] * bflo(v[q].z); a[5] += w[q] * bfhi(v[q].z);
                a[6] += w[q] * bflo(v[q].w); a[7] += w[q] * bfhi(v[q].w);
            }
        }
    }

#pragma unroll
    for (int k = 0; k < 8; ++k) {
        a[k] += __shfl_xor(a[k], 16);
        a[k] += __shfl_xor(a[k], 32);
    }

    if (eslot == 0) {
        float d = dinv[node];
        uint4 vs = hp4[(long)node * 16 + ug];
        a[0] += d * bflo(vs.x); a[1] += d * bfhi(vs.x);
        a[2] += d * bflo(vs.y); a[3] += d * bfhi(vs.y);
        a[4] += d * bflo(vs.z); a[5] += d * bfhi(vs.z);
        a[6] += d * bflo(vs.w); a[7] += d * bfhi(vs.w);
        float4 b0 = *(const float4*)(bias + ug * 8);
        float4 b1 = *(const float4*)(bias + ug * 8 + 4);
        float o0 = fmaxf(d * a[0] + b0.x, 0.f), o1 = fmaxf(d * a[1] + b0.y, 0.f);
        float o2 = fmaxf(d * a[2] + b0.z, 0.f), o3 = fmaxf(d * a[3] + b0.w, 0.f);
        float o4 = fmaxf(d * a[4] + b1.x, 0.f), o5 = fmaxf(d * a[5] + b1.y, 0.f);
        float o6 = fmaxf(d * a[6] + b1.z, 0.f), o7 = fmaxf(d * a[7] + b1.w, 0.f);
        uint4 o;
        o.x = (unsigned)f2bf(o0) | ((unsigned)f2bf(o1) << 16);
        o.y = (unsigned)f2bf(o2) | ((unsigned)f2bf(o3) << 16);
        o.z = (unsigned)f2bf(o4) | ((unsigned)f2bf(o5) << 16);
        o.w = (unsigned)f2bf(o6) | ((unsigned)f2bf(o7) << 16);
        hout4[(long)node * 16 + ug] = o;
    }
}

// ---- pool + head body (one graph, 256 threads) ----
__device__ __forceinline__ void pool_body(int g, int tid, const unsigned short* __restrict__ h,
                                          const int* __restrict__ batch, const float* __restrict__ Wlin,
                                          const float* __restrict__ blin, float* __restrict__ out,
                                          int* sm) {
    int* bnd = sm + 1024;
    float* smf = (float*)sm;
    if (tid < 2) {
        int target = g + tid;
        int lo = 0, hi = N_NODES;
        while (lo < hi) {
            int mid = (lo + hi) >> 1;
            if (batch[mid] < target) lo = mid + 1;
            else hi = mid;
        }
        bnd[tid] = lo;
    }
    __syncthreads();
    int s = bnd[0], e = bnd[1];
    int c = tid & 127, half = tid >> 7;
    float sum = 0.f;
    for (int i = s + half; i < e; i += 2) {
        union { unsigned u; float f; } v;
        v.u = (unsigned)h[(long)i * 128 + c] << 16;
        sum += v.f;
    }
    smf[tid] = sum;
    __syncthreads();
    if (half == 0) {
        float tsum = smf[c] + smf[c + 128];
        float inv = (e > s) ? 1.0f / (float)(e - s) : 1.0f;
        float m = tsum * inv;
        smf[256 + c * 2 + 0] = m * Wlin[c * 2 + 0];
        smf[256 + c * 2 + 1] = m * Wlin[c * 2 + 1];
    }
    __syncthreads();
    for (int off = 64; off > 0; off >>= 1) {
        if (tid < off) {
            smf[256 + tid * 2 + 0] += smf[256 + (tid + off) * 2 + 0];
            smf[256 + tid * 2 + 1] += smf[256 + (tid + off) * 2 + 1];
        }
        __syncthreads();
    }
    if (tid < 2) out[g * 2 + tid] = smf[256 + tid] + blin[tid];
    __syncthreads();
}

// ==================== the kernel (phase < 0: cooperative all-phases) ====================
__global__ __launch_bounds__(256, 4) void gcn_mega(
    int phase,
    const float* __restrict__ x, const int* __restrict__ ei, const int* __restrict__ batch,
    const float* __restrict__ W1, const float* __restrict__ b1,
    const float* __restrict__ W2, const float* __restrict__ b2,
    const float* __restrict__ Wlin, const float* __restrict__ blin,
    float* __restrict__ out, char* __restrict__ ws) {
    __shared__ int sm[1280];
    const int bid = blockIdx.x;
    const int tid = threadIdx.x;
    const int nblk = gridDim.x;

    const int* src = ei;
    const int* dst = ei + N_EDGES;

    const size_t KB = 1024, MB = 1048576;
    float* dinv     = (float*)(ws);
    int*   cnt      = (int*)  (ws + 256 * KB);
    int*   rowstart = (int*)  (ws + 512 * KB);
    int*   bstart   = (int*)  (ws + 768 * KB);         // 197 ints
    int*   total    = (int*)  (ws + 772 * KB);         // 196 ints
    int*   bh       = (int*)  (ws + 1 * MB);           // 512*196 ints = 400 KB
    int*   goff     = (int*)  (ws + 2 * MB);           // 400 KB
    uint2* ebuf     = (uint2*)(ws + 3 * MB);           // 6.4 MB
    int*   esrc     = (int*)  (ws + 10 * MB);          // 3.2 MB
    unsigned short* W1f = (unsigned short*)(ws + 14 * MB);
    unsigned short* W2f = (unsigned short*)(ws + 14 * MB + 64 * KB);
    unsigned short* hp  = (unsigned short*)(ws + 15 * MB);   // N_PAD x 128 bf16
    unsigned short* h   = (unsigned short*)(ws + 28 * MB);   // N_PAD x 128 bf16

    if (phase < 0) {
        cg::grid_group grid = cg::this_grid();
        ph_hist(bid, tid, nblk, dst, W1, W2, W1f, W2f, bh, sm);
        grid.sync();
        ph_totals(bid, tid, nblk, bh, total, sm);
        grid.sync();
        ph_goff(bid, tid, nblk, bh, total, bstart, goff, sm);
        grid.sync();
        ph_scatter(bid, tid, nblk, src, dst, goff, ebuf, sm);
        grid.sync();
        for (int v = bid; v < NBUCK + NB_G; v += nblk) {
            if (v < NBUCK) bsort_body(v, tid, ebuf, bstart, rowstart, cnt, dinv, esrc, sm);
            else gemm1_body(v - NBUCK, tid, x, W1f, hp);
        }
        grid.sync();
        for (int v = bid; v < NB_AG; v += nblk)
            aggregate_body(v, tid, (const uint4*)hp, esrc, rowstart, cnt, dinv, b1, (uint4*)h);
        grid.sync();
        for (int v = bid; v < NB_G; v += nblk)
            gemm2_body(v, tid, h, W2f, hp);
        grid.sync();
        for (int v = bid; v < NB_AG; v += nblk)
            aggregate_body(v, tid, (const uint4*)hp, esrc, rowstart, cnt, dinv, b2, (uint4*)h);
        grid.sync();
        for (int g = bid; g < N_GRAPHS; g += nblk)
            pool_body(g, tid, h, batch, Wlin, blin, out, sm);
    } else {
        switch (phase) {
            case 0: ph_hist(bid, tid, nblk, dst, W1, W2, W1f, W2f, bh, sm); break;
            case 1: ph_totals(bid, tid, nblk, bh, total, sm); break;
            case 2: ph_goff(bid, tid, nblk, bh, total, bstart, goff, sm); break;
            case 3: ph_scatter(bid, tid, nblk, src, dst, goff, ebuf, sm); break;
            case 4:
                for (int v = bid; v < NBUCK + NB_G; v += nblk) {
                    if (v < NBUCK) bsort_body(v, tid, ebuf, bstart, rowstart, cnt, dinv, esrc, sm);
                    else gemm1_body(v - NBUCK, tid, x, W1f, hp);
                }
                break;
            case 5:
                for (int v = bid; v < NB_AG; v += nblk)
                    aggregate_body(v, tid, (const uint4*)hp, esrc, rowstart, cnt, dinv, b1, (uint4*)h);
                break;
            case 6:
                for (int v = bid; v < NB_G; v += nblk)
                    gemm2_body(v, tid, h, W2f, hp);
                break;
            case 7:
                for (int v = bid; v < NB_AG; v += nblk)
                    aggregate_body(v, tid, (const uint4*)hp, esrc, rowstart, cnt, dinv, b2, (uint4*)h);
                break;
            case 8:
                for (int g = bid; g < N_GRAPHS; g += nblk)
                    pool_body(g, tid, h, batch, Wlin, blin, out, sm);
                break;
        }
    }
}

extern "C" void kernel_launch(void* const* d_in, const int* in_sizes, int n_in,
                              void* d_out, int out_size, void* d_ws, size_t ws_size,
                              hipStream_t stream) {
    const float* x    = (const float*)d_in[0];
    const int*   ei   = (const int*)d_in[1];
    const int*   batch= (const int*)d_in[2];
    const float* W1   = (const float*)d_in[4];
    const float* b1   = (const float*)d_in[5];
    const float* W2   = (const float*)d_in[6];
    const float* b2   = (const float*)d_in[7];
    const float* Wlin = (const float*)d_in[8];
    const float* blin = (const float*)d_in[9];
    float* out = (float*)d_out;
    char* wsb = (char*)d_ws;

    // size the cooperative grid from ACTUAL occupancy (capture-safe host queries)
    int dev = 0;
    hipGetDevice(&dev);
    int ncu = 0;
    hipDeviceGetAttribute(&ncu, hipDeviceAttributeMultiprocessorCount, dev);
    int nbpc = 0;
    hipOccupancyMaxActiveBlocksPerMultiprocessor(&nbpc, gcn_mega, 256, 0);
    long long cap = (long long)nbpc * (long long)ncu;
    int grid = (int)(cap > 1024 ? 1024 : cap);

    hipError_t err = hipErrorUnknown;
    if (grid >= 64) {
        int phase = -1;
        void* args[] = {&phase, &x, &ei, &batch, &W1, &b1, &W2, &b2, &Wlin, &blin, &out, &wsb};
        err = hipLaunchCooperativeKernel((void*)gcn_mega, dim3(grid), dim3(256), args, 0, stream);
    }
    if (err != hipSuccess) {
        // fallback: same kernel, one phase per normal dispatch (no grid.sync on this path)
        for (int p = 0; p <= 8; ++p)
            hipLaunchKernelGGL(gcn_mega, dim3(1024), dim3(256), 0, stream,
                               p, x, ei, batch, W1, b1, W2, b2, Wlin, blin, out, wsb);
    }
}

// Round 11
// 265.153 us; speedup vs baseline: 3.0957x; 3.0957x over previous
//
#include <hip/hip_runtime.h>

#define N_NODES 50000
#define N_PAD   50048   // 782 * 64
#define N_EDGES 800000
#define N_GRAPHS 512
#define F_IN 96
#define HID 128
#define NBUCK 196       // buckets of 256 nodes (dst >> 8)
#define CHUNK 4096      // edges per chunk block

typedef __bf16 bf16x8 __attribute__((ext_vector_type(8)));
typedef float  f32x4  __attribute__((ext_vector_type(4)));

__device__ __forceinline__ unsigned short f2bf(float f) {
    union { float f; unsigned u; } v; v.f = f;
    unsigned r = v.u + 0x7FFFu + ((v.u >> 16) & 1u);  // RNE
    return (unsigned short)(r >> 16);
}
__device__ __forceinline__ float bflo(unsigned u) {
    union { unsigned u; float f; } v; v.u = u << 16; return v.f;
}
__device__ __forceinline__ float bfhi(unsigned u) {
    union { unsigned u; float f; } v; v.u = u & 0xFFFF0000u; return v.f;
}

// W f32 [K x 128] -> bf16 B-fragments: frag idx=(t*KS+s)*64+lane;
// element j: B[k=s*32+(lane>>4)*8+j][n=t*16+(lane&15)]
__device__ __forceinline__ void prep_one(const float* __restrict__ W, int KS, int idx,
                                         unsigned short* __restrict__ Wf) {
    int t = idx / (KS * 64);
    int rem = idx % (KS * 64);
    int s = rem / 64;
    int l = rem & 63;
    int n = t * 16 + (l & 15);
    int k0 = s * 32 + (l >> 4) * 8;
    unsigned short v[8];
#pragma unroll
    for (int j = 0; j < 8; ++j) v[j] = f2bf(W[(long)(k0 + j) * 128 + n]);
    uint4 o;
    o.x = (unsigned)v[0] | ((unsigned)v[1] << 16);
    o.y = (unsigned)v[2] | ((unsigned)v[3] << 16);
    o.z = (unsigned)v[4] | ((unsigned)v[5] << 16);
    o.w = (unsigned)v[6] | ((unsigned)v[7] << 16);
    *(uint4*)(Wf + (long)idx * 8) = o;
}

// ---- K1: chunk bucket-hists (uint4 dst) + W prep + zero cnt ----
__global__ __launch_bounds__(256) void k1_hist(const int* __restrict__ dst,
                                               const float* __restrict__ W1,
                                               const float* __restrict__ W2,
                                               unsigned short* __restrict__ W1f,
                                               unsigned short* __restrict__ W2f,
                                               int* __restrict__ bh,
                                               int* __restrict__ cnt) {
    int blk = blockIdx.x;
    int tid = threadIdx.x;
    if (blk < NBUCK) {  // chunk histogram
        __shared__ int bhist[NBUCK];
        for (int i = tid; i < NBUCK; i += 256) bhist[i] = 0;
        __syncthreads();
        int e0 = blk * CHUNK, e1 = min(e0 + CHUNK, N_EDGES);
        int n4 = (e1 - e0) >> 2;  // chunk sizes divisible by 4
        const uint4* d4 = (const uint4*)(dst + e0);
        for (int i = tid; i < n4; i += 256) {
            uint4 d = d4[i];
            atomicAdd(&bhist[d.x >> 8], 1);
            atomicAdd(&bhist[d.y >> 8], 1);
            atomicAdd(&bhist[d.z >> 8], 1);
            atomicAdd(&bhist[d.w >> 8], 1);
        }
        __syncthreads();
        for (int i = tid; i < NBUCK; i += 256) bh[blk * NBUCK + i] = bhist[i];
    } else if (blk < NBUCK + 14) {  // weight prep
        int b = blk - NBUCK;
        if (b < 6) { int idx = b * 256 + tid; if (idx < 8 * 3 * 64) prep_one(W1, 3, idx, W1f); }
        else { int idx = (b - 6) * 256 + tid; if (idx < 8 * 4 * 64) prep_one(W2, 4, idx, W2f); }
    } else {  // zero cnt (49 blocks x 1024)
        int i = (blk - NBUCK - 14) * 1024 + tid * 4;
        if (i < N_NODES + 48) *(int4*)(cnt + i) = make_int4(0, 0, 0, 0);
    }
}

// ---- K2: scan bh -> bstart/goff (block 0)  ||  node degree hist (blocks 1..782) ----
__global__ __launch_bounds__(256) void k2_scan(const int* __restrict__ bh,
                                               const int* __restrict__ dst,
                                               int* __restrict__ bstart,
                                               int* __restrict__ goff,
                                               int* __restrict__ cnt) {
    int tid = threadIdx.x;
    if (blockIdx.x == 0) {
        __shared__ int s[256];
        int b = tid;
        int total = 0;
        if (b < NBUCK)
            for (int c = 0; c < NBUCK; ++c) total += bh[c * NBUCK + b];
        s[b] = total;
        __syncthreads();
        for (int off = 1; off < 256; off <<= 1) {
            int t = 0;
            if (b >= off) t = s[b - off];
            __syncthreads();
            if (b >= off) s[b] += t;
            __syncthreads();
        }
        int ex = s[b] - total;
        if (b < NBUCK) {
            bstart[b] = ex;
            int run = ex;
            for (int c = 0; c < NBUCK; ++c) {
                goff[c * NBUCK + b] = run;
                run += bh[c * NBUCK + b];
            }
        }
        if (b == 0) bstart[NBUCK] = N_EDGES;
    } else {
        int gi = (blockIdx.x - 1) * 256 + tid;
        if (gi < N_EDGES / 4) {
            uint4 d = ((const uint4*)dst)[gi];
            atomicAdd(&cnt[d.x], 1);
            atomicAdd(&cnt[d.y], 1);
            atomicAdd(&cnt[d.z], 1);
            atomicAdd(&cnt[d.w], 1);
        }
    }
}

// ---- K3: scatter pairs (blocks 0..195)  ||  dinv (blocks 196..391) ----
__global__ __launch_bounds__(256) void k3_scatter(const int* __restrict__ src,
                                                  const int* __restrict__ dst,
                                                  const int* __restrict__ goff,
                                                  const int* __restrict__ cnt,
                                                  uint2* __restrict__ ebuf,
                                                  float* __restrict__ dinv) {
    int tid = threadIdx.x;
    int c = blockIdx.x;
    if (c < NBUCK) {
        __shared__ int lg[NBUCK];
        __shared__ int lc[NBUCK];
        for (int i = tid; i < NBUCK; i += 256) { lg[i] = goff[c * NBUCK + i]; lc[i] = 0; }
        __syncthreads();
        int e0 = c * CHUNK, e1 = min(e0 + CHUNK, N_EDGES);
        for (int e = e0 + tid; e < e1; e += 256) {
            int d = dst[e];
            int b = d >> 8;
            int slot = atomicAdd(&lc[b], 1);
            ebuf[lg[b] + slot] = make_uint2((unsigned)src[e], (unsigned)d);
        }
    } else {
        int i = (c - NBUCK) * 256 + tid;
        if (i < N_NODES) dinv[i] = rsqrtf((float)cnt[i] + 1.0f);
    }
}

// ---- K4: bucket_sort (blocks 0..195)  ||  gemm layer 1 (blocks 196..977) ----
__global__ __launch_bounds__(256) void k4_sort_gemm1(const uint2* __restrict__ ebuf,
                                                     const int* __restrict__ bstart,
                                                     int* __restrict__ rowstart,
                                                     int* __restrict__ esrc,
                                                     const float* __restrict__ x,
                                                     const unsigned short* __restrict__ W1f,
                                                     const float* __restrict__ dinv,
                                                     unsigned short* __restrict__ hp) {
    int tid = threadIdx.x;
    if (blockIdx.x < NBUCK) {
        __shared__ int lcnt[256];
        __shared__ int ssc[256];
        __shared__ int ncur[256];
        int b = blockIdx.x;
        int nbase = b * 256;
        int r0 = bstart[b], r1 = bstart[b + 1];
        lcnt[tid] = 0;
        __syncthreads();
        for (int i = r0 + tid; i < r1; i += 256)
            atomicAdd(&lcnt[(int)ebuf[i].y - nbase], 1);
        __syncthreads();
        int c = lcnt[tid];
        ssc[tid] = c;
        __syncthreads();
        for (int off = 1; off < 256; off <<= 1) {
            int t = 0;
            if (tid >= off) t = ssc[tid - off];
            __syncthreads();
            if (tid >= off) ssc[tid] += t;
            __syncthreads();
        }
        int rs = r0 + ssc[tid] - c;
        ncur[tid] = rs;
        int node = nbase + tid;
        if (node < N_NODES) rowstart[node] = rs;
        __syncthreads();
        for (int i = r0 + tid; i < r1; i += 256) {
            uint2 p = ebuf[i];
            int pos = atomicAdd(&ncur[(int)p.y - nbase], 1);
            esrc[pos] = (int)p.x;
        }
    } else {
        // gemm1: hp[row,:] = bf16(dinv[row] * (x[row,:] @ W1))
        const int KS = 3;
        int vb = blockIdx.x - NBUCK;
        const int wave = tid >> 6, lane = tid & 63;
        const int r0 = vb * 64 + wave * 16;
        f32x4 acc[8];
#pragma unroll
        for (int t = 0; t < 8; ++t) acc[t] = (f32x4){0.f, 0.f, 0.f, 0.f};
        int arow = r0 + (lane & 15);
        if (arow >= N_NODES) arow = N_NODES - 1;
        const int kq = (lane >> 4) * 8;
        for (int s = 0; s < KS; ++s) {
            const float* ap = x + (long)arow * F_IN + s * 32 + kq;
            float4 a0 = *(const float4*)(ap);
            float4 a1 = *(const float4*)(ap + 4);
            union { uint4 u; bf16x8 b; } af;
            af.u.x = (unsigned)f2bf(a0.x) | ((unsigned)f2bf(a0.y) << 16);
            af.u.y = (unsigned)f2bf(a0.z) | ((unsigned)f2bf(a0.w) << 16);
            af.u.z = (unsigned)f2bf(a1.x) | ((unsigned)f2bf(a1.y) << 16);
            af.u.w = (unsigned)f2bf(a1.z) | ((unsigned)f2bf(a1.w) << 16);
#pragma unroll
            for (int t = 0; t < 8; ++t) {
                union { uint4 u; bf16x8 b; } bfr;
                bfr.u = *(const uint4*)(W1f + ((long)(t * KS + s) * 64 + lane) * 8);
                acc[t] = __builtin_amdgcn_mfma_f32_16x16x32_bf16(af.b, bfr.b, acc[t], 0, 0, 0);
            }
        }
        const int q = lane >> 4;
        float dv[4];
#pragma unroll
        for (int r = 0; r < 4; ++r) {
            int row = r0 + q * 4 + r;
            dv[r] = dinv[row < N_NODES ? row : 0];
        }
#pragma unroll
        for (int t = 0; t < 8; ++t) {
            int col = t * 16 + (lane & 15);
#pragma unroll
            for (int r = 0; r < 4; ++r) {
                int row = r0 + q * 4 + r;
                if (row < N_NODES) hp[(long)row * 128 + col] = f2bf(acc[t][r] * dv[r]);
            }
        }
    }
}

// ---- gemm layer 2: hp = bf16(dinv * (h @ W2)) ----
__global__ __launch_bounds__(256) void gemm_mfma_bf16A(const unsigned short* __restrict__ A,
                                                       const unsigned short* __restrict__ Wf,
                                                       const float* __restrict__ dinv,
                                                       unsigned short* __restrict__ hp) {
    const int KS = 4;
    const int wave = threadIdx.x >> 6;
    const int lane = threadIdx.x & 63;
    const int r0 = blockIdx.x * 64 + wave * 16;

    f32x4 acc[8];
#pragma unroll
    for (int t = 0; t < 8; ++t) acc[t] = (f32x4){0.f, 0.f, 0.f, 0.f};

    const int arow = r0 + (lane & 15);   // pad-row reads land in ws padding: safe
    const int kq = (lane >> 4) * 8;

    for (int s = 0; s < KS; ++s) {
        union { uint4 u; bf16x8 b; } af;
        af.u = *(const uint4*)(A + (long)arow * HID + s * 32 + kq);
#pragma unroll
        for (int t = 0; t < 8; ++t) {
            union { uint4 u; bf16x8 b; } bfr;
            bfr.u = *(const uint4*)(Wf + ((long)(t * KS + s) * 64 + lane) * 8);
            acc[t] = __builtin_amdgcn_mfma_f32_16x16x32_bf16(af.b, bfr.b, acc[t], 0, 0, 0);
        }
    }

    const int q = lane >> 4;
    float dv[4];
#pragma unroll
    for (int r = 0; r < 4; ++r) {
        int row = r0 + q * 4 + r;
        dv[r] = dinv[row < N_NODES ? row : 0];
    }
#pragma unroll
    for (int t = 0; t < 8; ++t) {
        int col = t * 16 + (lane & 15);
#pragma unroll
        for (int r = 0; r < 4; ++r) {
            int row = r0 + q * 4 + r;
            if (row < N_NODES)
                hp[(long)row * 128 + col] = f2bf(acc[t][r] * dv[r]);
        }
    }
}

// ---- aggregate: wave/node, 16 lanes x dwordx4 (R8-proven) ----
__global__ __launch_bounds__(256) void aggregate4(const uint4* __restrict__ hp4,
                                                  const int* __restrict__ esrc,
                                                  const int* __restrict__ rowstart,
                                                  const int* __restrict__ cnt,
                                                  const float* __restrict__ dinv,
                                                  const float* __restrict__ bias,
                                                  uint4* __restrict__ hout4) {
    int node = blockIdx.x * 4 + (threadIdx.x >> 6);
    if (node >= N_NODES) return;
    int lane = threadIdx.x & 63;
    int eslot = lane >> 4;
    int ug = lane & 15;
    int start = rowstart[node];
    int end = start + cnt[node];

    float a[8];
#pragma unroll
    for (int k = 0; k < 8; ++k) a[k] = 0.f;

    for (int j = start; j < end; j += 16) {
        int e[4];
        uint4 v[4];
#pragma unroll
        for (int q = 0; q < 4; ++q) {
            e[q] = j + q * 4 + eslot;
            int s = esrc[min(e[q], end - 1)];
            v[q] = hp4[(long)s * 16 + ug];
        }
#pragma unroll
        for (int q = 0; q < 4; ++q) {
            if (e[q] < end) {
                a[0] += bflo(v[q].x); a[1] += bfhi(v[q].x);
                a[2] += bflo(v[q].y); a[3] += bfhi(v[q].y);
                a[4] += bflo(v[q].z); a[5] += bfhi(v[q].z);
                a[6] += bflo(v[q].w); a[7] += bfhi(v[q].w);
            }
        }
    }

#pragma unroll
    for (int k = 0; k < 8; ++k) {
        a[k] += __shfl_xor(a[k], 16);
        a[k] += __shfl_xor(a[k], 32);
    }

    if (eslot == 0) {
        uint4 vs = hp4[(long)node * 16 + ug];
        a[0] += bflo(vs.x); a[1] += bfhi(vs.x);
        a[2] += bflo(vs.y); a[3] += bfhi(vs.y);
        a[4] += bflo(vs.z); a[5] += bfhi(vs.z);
        a[6] += bflo(vs.w); a[7] += bfhi(vs.w);
        float d = dinv[node];
        float4 b0 = *(const float4*)(bias + ug * 8);
        float4 b1 = *(const float4*)(bias + ug * 8 + 4);
        float o0 = fmaxf(d * a[0] + b0.x, 0.f), o1 = fmaxf(d * a[1] + b0.y, 0.f);
        float o2 = fmaxf(d * a[2] + b0.z, 0.f), o3 = fmaxf(d * a[3] + b0.w, 0.f);
        float o4 = fmaxf(d * a[4] + b1.x, 0.f), o5 = fmaxf(d * a[5] + b1.y, 0.f);
        float o6 = fmaxf(d * a[6] + b1.z, 0.f), o7 = fmaxf(d * a[7] + b1.w, 0.f);
        uint4 o;
        o.x = (unsigned)f2bf(o0) | ((unsigned)f2bf(o1) << 16);
        o.y = (unsigned)f2bf(o2) | ((unsigned)f2bf(o3) << 16);
        o.z = (unsigned)f2bf(o4) | ((unsigned)f2bf(o5) << 16);
        o.w = (unsigned)f2bf(o6) | ((unsigned)f2bf(o7) << 16);
        hout4[(long)node * 16 + ug] = o;
    }
}

// ---- pooling + head ----
__global__ __launch_bounds__(128) void pool_head(const unsigned short* __restrict__ h,
                                                 const int* __restrict__ batch,
                                                 const float* __restrict__ Wlin,
                                                 const float* __restrict__ blin,
                                                 float* __restrict__ out) {
    __shared__ int bnd[2];
    int g = blockIdx.x;
    int c = threadIdx.x;
    if (c < 2) {
        int target = g + c;
        int lo = 0, hi = N_NODES;
        while (lo < hi) {
            int mid = (lo + hi) >> 1;
            if (batch[mid] < target) lo = mid + 1;
            else hi = mid;
        }
        bnd[c] = lo;
    }
    __syncthreads();
    int s = bnd[0], e = bnd[1];

    float sum = 0.f;
    for (int i = s; i < e; ++i) {
        union { unsigned u; float f; } v;
        v.u = (unsigned)h[(long)i * 128 + c] << 16;
        sum += v.f;
    }
    float inv = (e > s) ? 1.0f / (float)(e - s) : 1.0f;
    float m = sum * inv;

    __shared__ float red[128][2];
    red[c][0] = m * Wlin[c * 2 + 0];
    red[c][1] = m * Wlin[c * 2 + 1];
    __syncthreads();
#pragma unroll
    for (int off = 64; off > 0; off >>= 1) {
        if (c < off) {
            red[c][0] += red[c + off][0];
            red[c][1] += red[c + off][1];
        }
        __syncthreads();
    }
    if (c < 2) out[g * 2 + c] = red[0][c] + blin[c];
}

extern "C" void kernel_launch(void* const* d_in, const int* in_sizes, int n_in,
                              void* d_out, int out_size, void* d_ws, size_t ws_size,
                              hipStream_t stream) {
    const float* x    = (const float*)d_in[0];
    const int*   ei   = (const int*)d_in[1];
    const int*   batch= (const int*)d_in[2];
    const float* W1   = (const float*)d_in[4];
    const float* b1   = (const float*)d_in[5];
    const float* W2   = (const float*)d_in[6];
    const float* b2   = (const float*)d_in[7];
    const float* Wlin = (const float*)d_in[8];
    const float* blin = (const float*)d_in[9];
    float* out = (float*)d_out;

    const int* src = ei;
    const int* dst = ei + N_EDGES;

    char* ws = (char*)d_ws;
    const size_t KB = 1024;
    const size_t MB = 1048576;

    float* dinv     = (float*)(ws);
    int*   cnt      = (int*)  (ws + 256 * KB);
    int*   rowstart = (int*)  (ws + 512 * KB);
    int*   bstart   = (int*)  (ws + 768 * KB);          // 197 ints
    int*   bh       = (int*)  (ws + 832 * KB);          // 196*196 ints = 154 KB
    int*   goff     = (int*)  (ws + 1 * MB);            // 154 KB
    uint2* ebuf     = (uint2*)(ws + 2 * MB);            // 6.4 MB
    int*   esrc     = (int*)  (ws + 9 * MB);            // 3.2 MB
    unsigned short* W1f = (unsigned short*)(ws + 12 * MB + 512 * KB);
    unsigned short* W2f = (unsigned short*)(ws + 12 * MB + 576 * KB);
    unsigned short* hp  = (unsigned short*)(ws + 13 * MB);   // N_PAD x 128 bf16
    unsigned short* h   = (unsigned short*)(ws + 26 * MB);   // N_PAD x 128 bf16

    const int NB_G  = N_PAD / 64;                 // 782
    const int NB_AG = (N_NODES + 3) / 4;          // 12500
    const int NB_Z  = (N_NODES + 48 + 1023) / 1024;  // 49

    // ---- CSR build (atomic-light, restructured for overlap) ----
    k1_hist<<<NBUCK + 14 + NB_Z, 256, 0, stream>>>(dst, W1, W2, W1f, W2f, bh, cnt);
    k2_scan<<<1 + (N_EDGES / 4 + 255) / 256, 256, 0, stream>>>(bh, dst, bstart, goff, cnt);
    k3_scatter<<<NBUCK + NBUCK, 256, 0, stream>>>(src, dst, goff, cnt, ebuf, dinv);
    k4_sort_gemm1<<<NBUCK + NB_G, 256, 0, stream>>>(ebuf, bstart, rowstart, esrc, x, W1f, dinv, hp);

    // ---- layer 1 aggregate ----
    aggregate4<<<NB_AG, 256, 0, stream>>>((const uint4*)hp, esrc, rowstart, cnt, dinv, b1, (uint4*)h);

    // ---- layer 2 ----
    gemm_mfma_bf16A<<<NB_G, 256, 0, stream>>>(h, W2f, dinv, hp);
    aggregate4<<<NB_AG, 256, 0, stream>>>((const uint4*)hp, esrc, rowstart, cnt, dinv, b2, (uint4*)h);

    // ---- pooling + head ----
    pool_head<<<N_GRAPHS, 128, 0, stream>>>(h, batch, Wlin, blin, out);
}

// Round 12
// 251.328 us; speedup vs baseline: 3.2660x; 1.0550x over previous
//
#include <hip/hip_runtime.h>

#define N_NODES 50000
#define N_PAD   50048   // 782 * 64
#define N_EDGES 800000
#define N_GRAPHS 512
#define F_IN 96
#define HID 128
#define NBUCK 196       // buckets of 256 nodes (dst >> 8)
#define CHUNK 4096      // edges per chunk block
#define NB_G 782        // gemm blocks (N_PAD/64)

typedef __bf16 bf16x8 __attribute__((ext_vector_type(8)));
typedef float  f32x4  __attribute__((ext_vector_type(4)));

__device__ __forceinline__ unsigned short f2bf(float f) {
    union { float f; unsigned u; } v; v.f = f;
    unsigned r = v.u + 0x7FFFu + ((v.u >> 16) & 1u);  // RNE
    return (unsigned short)(r >> 16);
}
__device__ __forceinline__ float bflo(unsigned u) {
    union { unsigned u; float f; } v; v.u = u << 16; return v.f;
}
__device__ __forceinline__ float bfhi(unsigned u) {
    union { unsigned u; float f; } v; v.u = u & 0xFFFF0000u; return v.f;
}

// build one B-fragment entry (8 bf16 = uint4) from f32 W[K x 128]
// frag idx=(t*KS+s)*64+lane; element j: B[k=s*32+(lane>>4)*8+j][n=t*16+(lane&15)]
__device__ __forceinline__ uint4 frag_of(const float* __restrict__ W, int KS, int idx) {
    int t = idx / (KS * 64);
    int rem = idx % (KS * 64);
    int s = rem / 64;
    int l = rem & 63;
    int n = t * 16 + (l & 15);
    int k0 = s * 32 + (l >> 4) * 8;
    unsigned short v[8];
#pragma unroll
    for (int j = 0; j < 8; ++j) v[j] = f2bf(W[(long)(k0 + j) * 128 + n]);
    uint4 o;
    o.x = (unsigned)v[0] | ((unsigned)v[1] << 16);
    o.y = (unsigned)v[2] | ((unsigned)v[3] << 16);
    o.z = (unsigned)v[4] | ((unsigned)v[5] << 16);
    o.w = (unsigned)v[6] | ((unsigned)v[7] << 16);
    return o;
}

// ---- K1: gemm1-raw (blocks 0..781)  ||  chunk hists (782..977)  ||  W2 prep (978..985) ----
// gemm1 emits RAW x@W1 (no dinv) -> zero dependency on the CSR chain.
__global__ __launch_bounds__(256) void k1_fused(const int* __restrict__ dst,
                                                const float* __restrict__ W1,
                                                const float* __restrict__ W2,
                                                unsigned short* __restrict__ W2f,
                                                int* __restrict__ bh,
                                                const float* __restrict__ x,
                                                unsigned short* __restrict__ hp) {
    __shared__ uint4 w1lds[1536];  // 24 KB: W1 fragments (or aliased as hist)
    int blk = blockIdx.x;
    int tid = threadIdx.x;

    if (blk < NB_G) {
        // build W1 fragments into LDS (KS=3 -> 8*3*64 = 1536 entries)
        for (int idx = tid; idx < 1536; idx += 256) w1lds[idx] = frag_of(W1, 3, idx);
        __syncthreads();

        const int KS = 3;
        const int wave = tid >> 6, lane = tid & 63;
        const int r0 = blk * 64 + wave * 16;
        f32x4 acc[8];
#pragma unroll
        for (int t = 0; t < 8; ++t) acc[t] = (f32x4){0.f, 0.f, 0.f, 0.f};
        int arow = r0 + (lane & 15);
        if (arow >= N_NODES) arow = N_NODES - 1;  // clamp; pad rows discarded on store
        const int kq = (lane >> 4) * 8;
        for (int s = 0; s < KS; ++s) {
            const float* ap = x + (long)arow * F_IN + s * 32 + kq;
            float4 a0 = *(const float4*)(ap);
            float4 a1 = *(const float4*)(ap + 4);
            union { uint4 u; bf16x8 b; } af;
            af.u.x = (unsigned)f2bf(a0.x) | ((unsigned)f2bf(a0.y) << 16);
            af.u.y = (unsigned)f2bf(a0.z) | ((unsigned)f2bf(a0.w) << 16);
            af.u.z = (unsigned)f2bf(a1.x) | ((unsigned)f2bf(a1.y) << 16);
            af.u.w = (unsigned)f2bf(a1.z) | ((unsigned)f2bf(a1.w) << 16);
#pragma unroll
            for (int t = 0; t < 8; ++t) {
                union { uint4 u; bf16x8 b; } bfr;
                bfr.u = w1lds[(t * KS + s) * 64 + lane];
                acc[t] = __builtin_amdgcn_mfma_f32_16x16x32_bf16(af.b, bfr.b, acc[t], 0, 0, 0);
            }
        }
        const int q = lane >> 4;
#pragma unroll
        for (int t = 0; t < 8; ++t) {
            int col = t * 16 + (lane & 15);
#pragma unroll
            for (int r = 0; r < 4; ++r) {
                int row = r0 + q * 4 + r;
                if (row < N_NODES) hp[(long)row * 128 + col] = f2bf(acc[t][r]);
            }
        }
    } else if (blk < NB_G + NBUCK) {
        int* bhist = (int*)w1lds;
        int c = blk - NB_G;
        for (int i = tid; i < NBUCK; i += 256) bhist[i] = 0;
        __syncthreads();
        int e0 = c * CHUNK, e1 = min(e0 + CHUNK, N_EDGES);
        int n4 = (e1 - e0) >> 2;  // chunk sizes divisible by 4
        const uint4* d4 = (const uint4*)(dst + e0);
        for (int i = tid; i < n4; i += 256) {
            uint4 d = d4[i];
            atomicAdd(&bhist[d.x >> 8], 1);
            atomicAdd(&bhist[d.y >> 8], 1);
            atomicAdd(&bhist[d.z >> 8], 1);
            atomicAdd(&bhist[d.w >> 8], 1);
        }
        __syncthreads();
        for (int i = tid; i < NBUCK; i += 256) bh[c * NBUCK + i] = bhist[i];
    } else {
        int idx = (blk - NB_G - NBUCK) * 256 + tid;  // 8 blocks x 256 = 2048 = 8*4*64
        *(uint4*)(W2f + (long)idx * 8) = frag_of(W2, 4, idx);
    }
}

// ---- K2: bucket starts + per-(chunk,bucket) offsets (1 block; R8-proven) ----
__global__ __launch_bounds__(256) void scan_all(const int* __restrict__ bh,
                                                int* __restrict__ bstart,
                                                int* __restrict__ goff) {
    __shared__ int s[256];
    int b = threadIdx.x;
    int total = 0;
    if (b < NBUCK)
        for (int c = 0; c < NBUCK; ++c) total += bh[c * NBUCK + b];
    s[b] = total;
    __syncthreads();
#pragma unroll
    for (int off = 1; off < 256; off <<= 1) {
        int t = 0;
        if (b >= off) t = s[b - off];
        __syncthreads();
        if (b >= off) s[b] += t;
        __syncthreads();
    }
    int ex = s[b] - total;
    if (b < NBUCK) {
        bstart[b] = ex;
        int run = ex;
        for (int c = 0; c < NBUCK; ++c) {
            goff[c * NBUCK + b] = run;
            run += bh[c * NBUCK + b];
        }
    }
    if (b == 0) bstart[NBUCK] = N_EDGES;
}

// ---- K3: scatter (src,dst) pairs bucket-grouped (R8-proven) ----
__global__ __launch_bounds__(256) void scatter_pairs(const int* __restrict__ src,
                                                     const int* __restrict__ dst,
                                                     const int* __restrict__ goff,
                                                     uint2* __restrict__ ebuf) {
    __shared__ int lgoff[NBUCK];
    __shared__ int lcur[NBUCK];
    int tid = threadIdx.x;
    int c = blockIdx.x;
    if (tid < NBUCK) {
        lgoff[tid] = goff[c * NBUCK + tid];
        lcur[tid] = 0;
    }
    __syncthreads();
    int e0 = c * CHUNK, e1 = min(e0 + CHUNK, N_EDGES);
    for (int e = e0 + tid; e < e1; e += 256) {
        int d = dst[e];
        int b = d >> 8;
        int slot = atomicAdd(&lcur[b], 1);
        ebuf[lgoff[b] + slot] = make_uint2((unsigned)src[e], (unsigned)d);
    }
}

// ---- K4: per-bucket count + scan + place; produces rowstart/cnt/dinv/esrc (R8-proven) ----
__global__ __launch_bounds__(256) void bucket_sort(const uint2* __restrict__ ebuf,
                                                   const int* __restrict__ bstart,
                                                   int* __restrict__ rowstart,
                                                   int* __restrict__ cnt,
                                                   float* __restrict__ dinv,
                                                   int* __restrict__ esrc) {
    __shared__ int lcnt[256];
    __shared__ int ssc[256];
    __shared__ int ncur[256];
    int b = blockIdx.x, tid = threadIdx.x;
    int nbase = b * 256;
    int r0 = bstart[b], r1 = bstart[b + 1];
    lcnt[tid] = 0;
    __syncthreads();
    for (int i = r0 + tid; i < r1; i += 256)
        atomicAdd(&lcnt[(int)ebuf[i].y - nbase], 1);
    __syncthreads();
    int c = lcnt[tid];
    ssc[tid] = c;
    __syncthreads();
#pragma unroll
    for (int off = 1; off < 256; off <<= 1) {
        int t = 0;
        if (tid >= off) t = ssc[tid - off];
        __syncthreads();
        if (tid >= off) ssc[tid] += t;
        __syncthreads();
    }
    int rs = r0 + ssc[tid] - c;
    ncur[tid] = rs;
    int node = nbase + tid;
    if (node < N_NODES) {
        rowstart[node] = rs;
        cnt[node] = c;
        dinv[node] = rsqrtf((float)c + 1.0f);
    }
    __syncthreads();
    for (int i = r0 + tid; i < r1; i += 256) {
        uint2 p = ebuf[i];
        int pos = atomicAdd(&ncur[(int)p.y - nbase], 1);
        esrc[pos] = (int)p.x;
    }
}

// ---- K5: aggregate layer 1 — hp is RAW; apply dinv_s per edge and dinv_d at epilogue ----
__global__ __launch_bounds__(256) void aggregate_w(const uint4* __restrict__ hp4,
                                                   const int* __restrict__ esrc,
                                                   const int* __restrict__ rowstart,
                                                   const int* __restrict__ cnt,
                                                   const float* __restrict__ dinv,
                                                   const float* __restrict__ bias,
                                                   uint4* __restrict__ hout4) {
    int node = blockIdx.x * 4 + (threadIdx.x >> 6);
    if (node >= N_NODES) return;
    int lane = threadIdx.x & 63;
    int eslot = lane >> 4;
    int ug = lane & 15;
    int start = rowstart[node];
    int end = start + cnt[node];

    float a[8];
#pragma unroll
    for (int k = 0; k < 8; ++k) a[k] = 0.f;

    for (int j = start; j < end; j += 16) {
        int e[4];
        uint4 v[4];
        float w[4];
#pragma unroll
        for (int q = 0; q < 4; ++q) {
            e[q] = j + q * 4 + eslot;
            int s = esrc[min(e[q], end - 1)];
            v[q] = hp4[(long)s * 16 + ug];
            w[q] = dinv[s];
        }
#pragma unroll
        for (int q = 0; q < 4; ++q) {
            if (e[q] < end) {
                a[0] += w[q] * bflo(v[q].x); a[1] += w[q] * bfhi(v[q].x);
                a[2] += w[q] * bflo(v[q].y); a[3] += w[q] * bfhi(v[q].y);
                a[4] += w[q] * bflo(v[q].z); a[5] += w[q] * bfhi(v[q].z);
                a[6] += w[q] * bflo(v[q].w); a[7] += w[q] * bfhi(v[q].w);
            }
        }
    }

#pragma unroll
    for (int k = 0; k < 8; ++k) {
        a[k] += __shfl_xor(a[k], 16);
        a[k] += __shfl_xor(a[k], 32);
    }

    if (eslot == 0) {
        float d = dinv[node];
        uint4 vs = hp4[(long)node * 16 + ug];
        a[0] += d * bflo(vs.x); a[1] += d * bfhi(vs.x);
        a[2] += d * bflo(vs.y); a[3] += d * bfhi(vs.y);
        a[4] += d * bflo(vs.z); a[5] += d * bfhi(vs.z);
        a[6] += d * bflo(vs.w); a[7] += d * bfhi(vs.w);
        float4 b0 = *(const float4*)(bias + ug * 8);
        float4 b1 = *(const float4*)(bias + ug * 8 + 4);
        float o0 = fmaxf(d * a[0] + b0.x, 0.f), o1 = fmaxf(d * a[1] + b0.y, 0.f);
        float o2 = fmaxf(d * a[2] + b0.z, 0.f), o3 = fmaxf(d * a[3] + b0.w, 0.f);
        float o4 = fmaxf(d * a[4] + b1.x, 0.f), o5 = fmaxf(d * a[5] + b1.y, 0.f);
        float o6 = fmaxf(d * a[6] + b1.z, 0.f), o7 = fmaxf(d * a[7] + b1.w, 0.f);
        uint4 o;
        o.x = (unsigned)f2bf(o0) | ((unsigned)f2bf(o1) << 16);
        o.y = (unsigned)f2bf(o2) | ((unsigned)f2bf(o3) << 16);
        o.z = (unsigned)f2bf(o4) | ((unsigned)f2bf(o5) << 16);
        o.w = (unsigned)f2bf(o6) | ((unsigned)f2bf(o7) << 16);
        hout4[(long)node * 16 + ug] = o;
    }
}

// ---- K6: gemm layer 2: hp = bf16(dinv * (h @ W2))  (R8-proven) ----
__global__ __launch_bounds__(256) void gemm_mfma_bf16A(const unsigned short* __restrict__ A,
                                                       const unsigned short* __restrict__ Wf,
                                                       const float* __restrict__ dinv,
                                                       unsigned short* __restrict__ hp) {
    const int KS = 4;
    const int wave = threadIdx.x >> 6;
    const int lane = threadIdx.x & 63;
    const int r0 = blockIdx.x * 64 + wave * 16;

    f32x4 acc[8];
#pragma unroll
    for (int t = 0; t < 8; ++t) acc[t] = (f32x4){0.f, 0.f, 0.f, 0.f};

    const int arow = r0 + (lane & 15);   // pad-row reads land in ws padding: safe
    const int kq = (lane >> 4) * 8;

    for (int s = 0; s < KS; ++s) {
        union { uint4 u; bf16x8 b; } af;
        af.u = *(const uint4*)(A + (long)arow * HID + s * 32 + kq);
#pragma unroll
        for (int t = 0; t < 8; ++t) {
            union { uint4 u; bf16x8 b; } bfr;
            bfr.u = *(const uint4*)(Wf + ((long)(t * KS + s) * 64 + lane) * 8);
            acc[t] = __builtin_amdgcn_mfma_f32_16x16x32_bf16(af.b, bfr.b, acc[t], 0, 0, 0);
        }
    }

    const int q = lane >> 4;
    float dv[4];
#pragma unroll
    for (int r = 0; r < 4; ++r) {
        int row = r0 + q * 4 + r;
        dv[r] = dinv[row < N_NODES ? row : 0];
    }
#pragma unroll
    for (int t = 0; t < 8; ++t) {
        int col = t * 16 + (lane & 15);
#pragma unroll
        for (int r = 0; r < 4; ++r) {
            int row = r0 + q * 4 + r;
            if (row < N_NODES)
                hp[(long)row * 128 + col] = f2bf(acc[t][r] * dv[r]);
        }
    }
}

// ---- K7: aggregate layer 2 — hp pre-scaled (R8-proven form) ----
__global__ __launch_bounds__(256) void aggregate4(const uint4* __restrict__ hp4,
                                                  const int* __restrict__ esrc,
                                                  const int* __restrict__ rowstart,
                                                  const int* __restrict__ cnt,
                                                  const float* __restrict__ dinv,
                                                  const float* __restrict__ bias,
                                                  uint4* __restrict__ hout4) {
    int node = blockIdx.x * 4 + (threadIdx.x >> 6);
    if (node >= N_NODES) return;
    int lane = threadIdx.x & 63;
    int eslot = lane >> 4;
    int ug = lane & 15;
    int start = rowstart[node];
    int end = start + cnt[node];

    float a[8];
#pragma unroll
    for (int k = 0; k < 8; ++k) a[k] = 0.f;

    for (int j = start; j < end; j += 16) {
        int e[4];
        uint4 v[4];
#pragma unroll
        for (int q = 0; q < 4; ++q) {
            e[q] = j + q * 4 + eslot;
            int s = esrc[min(e[q], end - 1)];
            v[q] = hp4[(long)s * 16 + ug];
        }
#pragma unroll
        for (int q = 0; q < 4; ++q) {
            if (e[q] < end) {
                a[0] += bflo(v[q].x); a[1] += bfhi(v[q].x);
                a[2] += bflo(v[q].y); a[3] += bfhi(v[q].y);
                a[4] += bflo(v[q].z); a[5] += bfhi(v[q].z);
                a[6] += bflo(v[q].w); a[7] += bfhi(v[q].w);
            }
        }
    }

#pragma unroll
    for (int k = 0; k < 8; ++k) {
        a[k] += __shfl_xor(a[k], 16);
        a[k] += __shfl_xor(a[k], 32);
    }

    if (eslot == 0) {
        uint4 vs = hp4[(long)node * 16 + ug];
        a[0] += bflo(vs.x); a[1] += bfhi(vs.x);
        a[2] += bflo(vs.y); a[3] += bfhi(vs.y);
        a[4] += bflo(vs.z); a[5] += bfhi(vs.z);
        a[6] += bflo(vs.w); a[7] += bfhi(vs.w);
        float d = dinv[node];
        float4 b0 = *(const float4*)(bias + ug * 8);
        float4 b1 = *(const float4*)(bias + ug * 8 + 4);
        float o0 = fmaxf(d * a[0] + b0.x, 0.f), o1 = fmaxf(d * a[1] + b0.y, 0.f);
        float o2 = fmaxf(d * a[2] + b0.z, 0.f), o3 = fmaxf(d * a[3] + b0.w, 0.f);
        float o4 = fmaxf(d * a[4] + b1.x, 0.f), o5 = fmaxf(d * a[5] + b1.y, 0.f);
        float o6 = fmaxf(d * a[6] + b1.z, 0.f), o7 = fmaxf(d * a[7] + b1.w, 0.f);
        uint4 o;
        o.x = (unsigned)f2bf(o0) | ((unsigned)f2bf(o1) << 16);
        o.y = (unsigned)f2bf(o2) | ((unsigned)f2bf(o3) << 16);
        o.z = (unsigned)f2bf(o4) | ((unsigned)f2bf(o5) << 16);
        o.w = (unsigned)f2bf(o6) | ((unsigned)f2bf(o7) << 16);
        hout4[(long)node * 16 + ug] = o;
    }
}

// ---- K8: pooling + head (R8-proven) ----
__global__ __launch_bounds__(128) void pool_head(const unsigned short* __restrict__ h,
                                                 const int* __restrict__ batch,
                                                 const float* __restrict__ Wlin,
                                                 const float* __restrict__ blin,
                                                 float* __restrict__ out) {
    __shared__ int bnd[2];
    int g = blockIdx.x;
    int c = threadIdx.x;
    if (c < 2) {
        int target = g + c;
        int lo = 0, hi = N_NODES;
        while (lo < hi) {
            int mid = (lo + hi) >> 1;
            if (batch[mid] < target) lo = mid + 1;
            else hi = mid;
        }
        bnd[c] = lo;
    }
    __syncthreads();
    int s = bnd[0], e = bnd[1];

    float sum = 0.f;
    for (int i = s; i < e; ++i) {
        union { unsigned u; float f; } v;
        v.u = (unsigned)h[(long)i * 128 + c] << 16;
        sum += v.f;
    }
    float inv = (e > s) ? 1.0f / (float)(e - s) : 1.0f;
    float m = sum * inv;

    __shared__ float red[128][2];
    red[c][0] = m * Wlin[c * 2 + 0];
    red[c][1] = m * Wlin[c * 2 + 1];
    __syncthreads();
#pragma unroll
    for (int off = 64; off > 0; off >>= 1) {
        if (c < off) {
            red[c][0] += red[c + off][0];
            red[c][1] += red[c + off][1];
        }
        __syncthreads();
    }
    if (c < 2) out[g * 2 + c] = red[0][c] + blin[c];
}

extern "C" void kernel_launch(void* const* d_in, const int* in_sizes, int n_in,
                              void* d_out, int out_size, void* d_ws, size_t ws_size,
                              hipStream_t stream) {
    const float* x    = (const float*)d_in[0];
    const int*   ei   = (const int*)d_in[1];
    const int*   batch= (const int*)d_in[2];
    const float* W1   = (const float*)d_in[4];
    const float* b1   = (const float*)d_in[5];
    const float* W2   = (const float*)d_in[6];
    const float* b2   = (const float*)d_in[7];
    const float* Wlin = (const float*)d_in[8];
    const float* blin = (const float*)d_in[9];
    float* out = (float*)d_out;

    const int* src = ei;
    const int* dst = ei + N_EDGES;

    char* ws = (char*)d_ws;
    const size_t KB = 1024;
    const size_t MB = 1048576;

    float* dinv     = (float*)(ws);
    int*   cnt      = (int*)  (ws + 256 * KB);
    int*   rowstart = (int*)  (ws + 512 * KB);
    int*   bstart   = (int*)  (ws + 768 * KB);          // 197 ints
    int*   bh       = (int*)  (ws + 832 * KB);          // 196*196 ints = 154 KB
    int*   goff     = (int*)  (ws + 1 * MB);            // 154 KB
    uint2* ebuf     = (uint2*)(ws + 2 * MB);            // 6.4 MB
    int*   esrc     = (int*)  (ws + 9 * MB);            // 3.2 MB
    unsigned short* W2f = (unsigned short*)(ws + 12 * MB + 576 * KB);  // 32 KB
    unsigned short* hp  = (unsigned short*)(ws + 13 * MB);   // N_PAD x 128 bf16
    unsigned short* h   = (unsigned short*)(ws + 26 * MB);   // N_PAD x 128 bf16

    const int NB_AG = (N_NODES + 3) / 4;          // 12500

    // K1: gemm1-raw || chunk hists || W2 prep  (gemm blocks first = long pole first)
    k1_fused<<<NB_G + NBUCK + 8, 256, 0, stream>>>(dst, W1, W2, W2f, bh, x, hp);
    // K2..K4: CSR build (R8-proven kernels)
    scan_all<<<1, 256, 0, stream>>>(bh, bstart, goff);
    scatter_pairs<<<NBUCK, 256, 0, stream>>>(src, dst, goff, ebuf);
    bucket_sort<<<NBUCK, 256, 0, stream>>>(ebuf, bstart, rowstart, cnt, dinv, esrc);

    // K5: layer-1 aggregate with per-edge dinv (hp is raw)
    aggregate_w<<<NB_AG, 256, 0, stream>>>((const uint4*)hp, esrc, rowstart, cnt, dinv, b1, (uint4*)h);

    // K6/K7: layer 2 (pre-scaled gemm + plain aggregate)
    gemm_mfma_bf16A<<<NB_G, 256, 0, stream>>>(h, W2f, dinv, hp);
    aggregate4<<<NB_AG, 256, 0, stream>>>((const uint4*)hp, esrc, rowstart, cnt, dinv, b2, (uint4*)h);

    // K8: pooling + head
    pool_head<<<N_GRAPHS, 128, 0, stream>>>(h, batch, Wlin, blin, out);
}

// Round 13
// 241.805 us; speedup vs baseline: 3.3946x; 1.0394x over previous
//
#include <hip/hip_runtime.h>

#define N_NODES 50000
#define N_PAD   50048   // 782 * 64
#define N_EDGES 800000
#define N_GRAPHS 512
#define F_IN 96
#define HID 128
#define NBUCK 196       // buckets of 256 nodes (dst >> 8)
#define CHUNK 4096      // edges per chunk block
#define NB_G 782        // gemm blocks (N_PAD/64)

typedef __bf16 bf16x8 __attribute__((ext_vector_type(8)));
typedef float  f32x4  __attribute__((ext_vector_type(4)));

__device__ __forceinline__ unsigned short f2bf(float f) {
    union { float f; unsigned u; } v; v.f = f;
    unsigned r = v.u + 0x7FFFu + ((v.u >> 16) & 1u);  // RNE
    return (unsigned short)(r >> 16);
}
__device__ __forceinline__ float bflo(unsigned u) {
    union { unsigned u; float f; } v; v.u = u << 16; return v.f;
}
__device__ __forceinline__ float bfhi(unsigned u) {
    union { unsigned u; float f; } v; v.u = u & 0xFFFF0000u; return v.f;
}

// build one B-fragment entry (8 bf16 = uint4) from f32 W[K x 128]
// frag idx=(t*KS+s)*64+lane; element j: B[k=s*32+(lane>>4)*8+j][n=t*16+(lane&15)]
__device__ __forceinline__ uint4 frag_of(const float* __restrict__ W, int KS, int idx) {
    int t = idx / (KS * 64);
    int rem = idx % (KS * 64);
    int s = rem / 64;
    int l = rem & 63;
    int n = t * 16 + (l & 15);
    int k0 = s * 32 + (l >> 4) * 8;
    unsigned short v[8];
#pragma unroll
    for (int j = 0; j < 8; ++j) v[j] = f2bf(W[(long)(k0 + j) * 128 + n]);
    uint4 o;
    o.x = (unsigned)v[0] | ((unsigned)v[1] << 16);
    o.y = (unsigned)v[2] | ((unsigned)v[3] << 16);
    o.z = (unsigned)v[4] | ((unsigned)v[5] << 16);
    o.w = (unsigned)v[6] | ((unsigned)v[7] << 16);
    return o;
}

// ---- K1: gemm1-raw (blocks 0..781)  ||  chunk hists (782..977)  ||  W2 prep (978..985) ----
__global__ __launch_bounds__(256) void k1_fused(const int* __restrict__ dst,
                                                const float* __restrict__ W1,
                                                const float* __restrict__ W2,
                                                unsigned short* __restrict__ W2f,
                                                int* __restrict__ bh,
                                                const float* __restrict__ x,
                                                unsigned short* __restrict__ hp) {
    __shared__ uint4 w1lds[1536];  // 24 KB: W1 fragments (aliased as hist for hist blocks)
    int blk = blockIdx.x;
    int tid = threadIdx.x;

    if (blk < NB_G) {
        for (int idx = tid; idx < 1536; idx += 256) w1lds[idx] = frag_of(W1, 3, idx);
        __syncthreads();

        const int KS = 3;
        const int wave = tid >> 6, lane = tid & 63;
        const int r0 = blk * 64 + wave * 16;
        f32x4 acc[8];
#pragma unroll
        for (int t = 0; t < 8; ++t) acc[t] = (f32x4){0.f, 0.f, 0.f, 0.f};
        int arow = r0 + (lane & 15);
        if (arow >= N_NODES) arow = N_NODES - 1;  // clamp; pad rows discarded on store
        const int kq = (lane >> 4) * 8;
        for (int s = 0; s < KS; ++s) {
            const float* ap = x + (long)arow * F_IN + s * 32 + kq;
            float4 a0 = *(const float4*)(ap);
            float4 a1 = *(const float4*)(ap + 4);
            union { uint4 u; bf16x8 b; } af;
            af.u.x = (unsigned)f2bf(a0.x) | ((unsigned)f2bf(a0.y) << 16);
            af.u.y = (unsigned)f2bf(a0.z) | ((unsigned)f2bf(a0.w) << 16);
            af.u.z = (unsigned)f2bf(a1.x) | ((unsigned)f2bf(a1.y) << 16);
            af.u.w = (unsigned)f2bf(a1.z) | ((unsigned)f2bf(a1.w) << 16);
#pragma unroll
            for (int t = 0; t < 8; ++t) {
                union { uint4 u; bf16x8 b; } bfr;
                bfr.u = w1lds[(t * KS + s) * 64 + lane];
                acc[t] = __builtin_amdgcn_mfma_f32_16x16x32_bf16(af.b, bfr.b, acc[t], 0, 0, 0);
            }
        }
        const int q = lane >> 4;
#pragma unroll
        for (int t = 0; t < 8; ++t) {
            int col = t * 16 + (lane & 15);
#pragma unroll
            for (int r = 0; r < 4; ++r) {
                int row = r0 + q * 4 + r;
                if (row < N_NODES) hp[(long)row * 128 + col] = f2bf(acc[t][r]);
            }
        }
    } else if (blk < NB_G + NBUCK) {
        int* bhist = (int*)w1lds;
        int c = blk - NB_G;
        for (int i = tid; i < NBUCK; i += 256) bhist[i] = 0;
        __syncthreads();
        int e0 = c * CHUNK, e1 = min(e0 + CHUNK, N_EDGES);
        int n4 = (e1 - e0) >> 2;  // chunk sizes divisible by 4
        const uint4* d4 = (const uint4*)(dst + e0);
        for (int i = tid; i < n4; i += 256) {
            uint4 d = d4[i];
            atomicAdd(&bhist[d.x >> 8], 1);
            atomicAdd(&bhist[d.y >> 8], 1);
            atomicAdd(&bhist[d.z >> 8], 1);
            atomicAdd(&bhist[d.w >> 8], 1);
        }
        __syncthreads();
        for (int i = tid; i < NBUCK; i += 256) bh[c * NBUCK + i] = bhist[i];
    } else {
        int idx = (blk - NB_G - NBUCK) * 256 + tid;  // 8 blocks x 256 = 2048 = 8*4*64
        *(uint4*)(W2f + (long)idx * 8) = frag_of(W2, 4, idx);
    }
}

// ---- K2: per-bucket scan over chunks (196 independent scans, fully parallel) ----
// goff[c][b] = exclusive prefix of bh[.][b] over chunks (RELATIVE to bucket base);
// total[b] = bucket b's edge count.
__global__ __launch_bounds__(256) void goff_scan(const int* __restrict__ bh,
                                                 int* __restrict__ goff,
                                                 int* __restrict__ total) {
    __shared__ int s[256];
    int b = blockIdx.x;
    int c = threadIdx.x;
    int v = (c < NBUCK) ? bh[c * NBUCK + b] : 0;
    s[c] = v;
    __syncthreads();
#pragma unroll
    for (int off = 1; off < 256; off <<= 1) {
        int t = 0;
        if (c >= off) t = s[c - off];
        __syncthreads();
        if (c >= off) s[c] += t;
        __syncthreads();
    }
    if (c < NBUCK) goff[c * NBUCK + b] = s[c] - v;  // exclusive
    if (c == 255) total[b] = s[255];
}

// ---- K3: scatter pairs; bstart derived in-block from total[] (8-step LDS scan) ----
__global__ __launch_bounds__(256) void scatter_pairs(const int* __restrict__ src,
                                                     const int* __restrict__ dst,
                                                     const int* __restrict__ goff,
                                                     const int* __restrict__ total,
                                                     uint2* __restrict__ ebuf) {
    __shared__ int ts[256];
    __shared__ int lgoff[NBUCK];
    __shared__ int lcur[NBUCK];
    int tid = threadIdx.x;
    int c = blockIdx.x;
    int tv = (tid < NBUCK) ? total[tid] : 0;
    ts[tid] = tv;
    __syncthreads();
#pragma unroll
    for (int off = 1; off < 256; off <<= 1) {
        int t = 0;
        if (tid >= off) t = ts[tid - off];
        __syncthreads();
        if (tid >= off) ts[tid] += t;
        __syncthreads();
    }
    if (tid < NBUCK) {
        lgoff[tid] = goff[c * NBUCK + tid] + (ts[tid] - tv);  // + bstart[tid]
        lcur[tid] = 0;
    }
    __syncthreads();
    int e0 = c * CHUNK, e1 = min(e0 + CHUNK, N_EDGES);
    for (int e = e0 + tid; e < e1; e += 256) {
        int d = dst[e];
        int b = d >> 8;
        int slot = atomicAdd(&lcur[b], 1);
        ebuf[lgoff[b] + slot] = make_uint2((unsigned)src[e], (unsigned)d);
    }
}

// ---- K4: bucket sort; r0/r1 derived in-block from total[] ----
__global__ __launch_bounds__(256) void bucket_sort(const uint2* __restrict__ ebuf,
                                                   const int* __restrict__ total,
                                                   int* __restrict__ rowstart,
                                                   int* __restrict__ cnt,
                                                   float* __restrict__ dinv,
                                                   int* __restrict__ esrc) {
    __shared__ int ts[256];
    __shared__ int lcnt[256];
    __shared__ int ssc[256];
    __shared__ int ncur[256];
    int b = blockIdx.x, tid = threadIdx.x;
    int tv = (tid < NBUCK) ? total[tid] : 0;
    ts[tid] = tv;
    __syncthreads();
#pragma unroll
    for (int off = 1; off < 256; off <<= 1) {
        int t = 0;
        if (tid >= off) t = ts[tid - off];
        __syncthreads();
        if (tid >= off) ts[tid] += t;
        __syncthreads();
    }
    int r1 = ts[b];             // inclusive prefix at b
    int r0 = r1 - total[b];     // exclusive = bucket start
    int nbase = b * 256;
    lcnt[tid] = 0;
    __syncthreads();
    for (int i = r0 + tid; i < r1; i += 256)
        atomicAdd(&lcnt[(int)ebuf[i].y - nbase], 1);
    __syncthreads();
    int c = lcnt[tid];
    ssc[tid] = c;
    __syncthreads();
#pragma unroll
    for (int off = 1; off < 256; off <<= 1) {
        int t = 0;
        if (tid >= off) t = ssc[tid - off];
        __syncthreads();
        if (tid >= off) ssc[tid] += t;
        __syncthreads();
    }
    int rs = r0 + ssc[tid] - c;
    ncur[tid] = rs;
    int node = nbase + tid;
    if (node < N_NODES) {
        rowstart[node] = rs;
        cnt[node] = c;
        dinv[node] = rsqrtf((float)c + 1.0f);
    }
    __syncthreads();
    for (int i = r0 + tid; i < r1; i += 256) {
        uint2 p = ebuf[i];
        int pos = atomicAdd(&ncur[(int)p.y - nbase], 1);
        esrc[pos] = (int)p.x;
    }
}

// ---- K5: aggregate layer 1 — hp is RAW; apply dinv_s per edge, dinv_d at epilogue ----
__global__ __launch_bounds__(256) void aggregate_w(const uint4* __restrict__ hp4,
                                                   const int* __restrict__ esrc,
                                                   const int* __restrict__ rowstart,
                                                   const int* __restrict__ cnt,
                                                   const float* __restrict__ dinv,
                                                   const float* __restrict__ bias,
                                                   uint4* __restrict__ hout4) {
    int node = blockIdx.x * 4 + (threadIdx.x >> 6);
    if (node >= N_NODES) return;
    int lane = threadIdx.x & 63;
    int eslot = lane >> 4;
    int ug = lane & 15;
    int start = rowstart[node];
    int end = start + cnt[node];

    float a[8];
#pragma unroll
    for (int k = 0; k < 8; ++k) a[k] = 0.f;

    for (int j = start; j < end; j += 16) {
        int e[4];
        uint4 v[4];
        float w[4];
#pragma unroll
        for (int q = 0; q < 4; ++q) {
            e[q] = j + q * 4 + eslot;
            int s = esrc[min(e[q], end - 1)];
            v[q] = hp4[(long)s * 16 + ug];
            w[q] = dinv[s];
        }
#pragma unroll
        for (int q = 0; q < 4; ++q) {
            if (e[q] < end) {
                a[0] += w[q] * bflo(v[q].x); a[1] += w[q] * bfhi(v[q].x);
                a[2] += w[q] * bflo(v[q].y); a[3] += w[q] * bfhi(v[q].y);
                a[4] += w[q] * bflo(v[q].z); a[5] += w[q] * bfhi(v[q].z);
                a[6] += w[q] * bflo(v[q].w); a[7] += w[q] * bfhi(v[q].w);
            }
        }
    }

#pragma unroll
    for (int k = 0; k < 8; ++k) {
        a[k] += __shfl_xor(a[k], 16);
        a[k] += __shfl_xor(a[k], 32);
    }

    if (eslot == 0) {
        float d = dinv[node];
        uint4 vs = hp4[(long)node * 16 + ug];
        a[0] += d * bflo(vs.x); a[1] += d * bfhi(vs.x);
        a[2] += d * bflo(vs.y); a[3] += d * bfhi(vs.y);
        a[4] += d * bflo(vs.z); a[5] += d * bfhi(vs.z);
        a[6] += d * bflo(vs.w); a[7] += d * bfhi(vs.w);
        float4 b0 = *(const float4*)(bias + ug * 8);
        float4 b1 = *(const float4*)(bias + ug * 8 + 4);
        float o0 = fmaxf(d * a[0] + b0.x, 0.f), o1 = fmaxf(d * a[1] + b0.y, 0.f);
        float o2 = fmaxf(d * a[2] + b0.z, 0.f), o3 = fmaxf(d * a[3] + b0.w, 0.f);
        float o4 = fmaxf(d * a[4] + b1.x, 0.f), o5 = fmaxf(d * a[5] + b1.y, 0.f);
        float o6 = fmaxf(d * a[6] + b1.z, 0.f), o7 = fmaxf(d * a[7] + b1.w, 0.f);
        uint4 o;
        o.x = (unsigned)f2bf(o0) | ((unsigned)f2bf(o1) << 16);
        o.y = (unsigned)f2bf(o2) | ((unsigned)f2bf(o3) << 16);
        o.z = (unsigned)f2bf(o4) | ((unsigned)f2bf(o5) << 16);
        o.w = (unsigned)f2bf(o6) | ((unsigned)f2bf(o7) << 16);
        hout4[(long)node * 16 + ug] = o;
    }
}

// ---- K6: gemm layer 2: hp = bf16(dinv * (h @ W2)) ----
__global__ __launch_bounds__(256) void gemm_mfma_bf16A(const unsigned short* __restrict__ A,
                                                       const unsigned short* __restrict__ Wf,
                                                       const float* __restrict__ dinv,
                                                       unsigned short* __restrict__ hp) {
    const int KS = 4;
    const int wave = threadIdx.x >> 6;
    const int lane = threadIdx.x & 63;
    const int r0 = blockIdx.x * 64 + wave * 16;

    f32x4 acc[8];
#pragma unroll
    for (int t = 0; t < 8; ++t) acc[t] = (f32x4){0.f, 0.f, 0.f, 0.f};

    const int arow = r0 + (lane & 15);   // pad-row reads land in ws padding: safe
    const int kq = (lane >> 4) * 8;

    for (int s = 0; s < KS; ++s) {
        union { uint4 u; bf16x8 b; } af;
        af.u = *(const uint4*)(A + (long)arow * HID + s * 32 + kq);
#pragma unroll
        for (int t = 0; t < 8; ++t) {
            union { uint4 u; bf16x8 b; } bfr;
            bfr.u = *(const uint4*)(Wf + ((long)(t * KS + s) * 64 + lane) * 8);
            acc[t] = __builtin_amdgcn_mfma_f32_16x16x32_bf16(af.b, bfr.b, acc[t], 0, 0, 0);
        }
    }

    const int q = lane >> 4;
    float dv[4];
#pragma unroll
    for (int r = 0; r < 4; ++r) {
        int row = r0 + q * 4 + r;
        dv[r] = dinv[row < N_NODES ? row : 0];
    }
#pragma unroll
    for (int t = 0; t < 8; ++t) {
        int col = t * 16 + (lane & 15);
#pragma unroll
        for (int r = 0; r < 4; ++r) {
            int row = r0 + q * 4 + r;
            if (row < N_NODES)
                hp[(long)row * 128 + col] = f2bf(acc[t][r] * dv[r]);
        }
    }
}

// ---- K7: aggregate layer 2 — hp pre-scaled ----
__global__ __launch_bounds__(256) void aggregate4(const uint4* __restrict__ hp4,
                                                  const int* __restrict__ esrc,
                                                  const int* __restrict__ rowstart,
                                                  const int* __restrict__ cnt,
                                                  const float* __restrict__ dinv,
                                                  const float* __restrict__ bias,
                                                  uint4* __restrict__ hout4) {
    int node = blockIdx.x * 4 + (threadIdx.x >> 6);
    if (node >= N_NODES) return;
    int lane = threadIdx.x & 63;
    int eslot = lane >> 4;
    int ug = lane & 15;
    int start = rowstart[node];
    int end = start + cnt[node];

    float a[8];
#pragma unroll
    for (int k = 0; k < 8; ++k) a[k] = 0.f;

    for (int j = start; j < end; j += 16) {
        int e[4];
        uint4 v[4];
#pragma unroll
        for (int q = 0; q < 4; ++q) {
            e[q] = j + q * 4 + eslot;
            int s = esrc[min(e[q], end - 1)];
            v[q] = hp4[(long)s * 16 + ug];
        }
#pragma unroll
        for (int q = 0; q < 4; ++q) {
            if (e[q] < end) {
                a[0] += bflo(v[q].x); a[1] += bfhi(v[q].x);
                a[2] += bflo(v[q].y); a[3] += bfhi(v[q].y);
                a[4] += bflo(v[q].z); a[5] += bfhi(v[q].z);
                a[6] += bflo(v[q].w); a[7] += bfhi(v[q].w);
            }
        }
    }

#pragma unroll
    for (int k = 0; k < 8; ++k) {
        a[k] += __shfl_xor(a[k], 16);
        a[k] += __shfl_xor(a[k], 32);
    }

    if (eslot == 0) {
        uint4 vs = hp4[(long)node * 16 + ug];
        a[0] += bflo(vs.x); a[1] += bfhi(vs.x);
        a[2] += bflo(vs.y); a[3] += bfhi(vs.y);
        a[4] += bflo(vs.z); a[5] += bfhi(vs.z);
        a[6] += bflo(vs.w); a[7] += bfhi(vs.w);
        float d = dinv[node];
        float4 b0 = *(const float4*)(bias + ug * 8);
        float4 b1 = *(const float4*)(bias + ug * 8 + 4);
        float o0 = fmaxf(d * a[0] + b0.x, 0.f), o1 = fmaxf(d * a[1] + b0.y, 0.f);
        float o2 = fmaxf(d * a[2] + b0.z, 0.f), o3 = fmaxf(d * a[3] + b0.w, 0.f);
        float o4 = fmaxf(d * a[4] + b1.x, 0.f), o5 = fmaxf(d * a[5] + b1.y, 0.f);
        float o6 = fmaxf(d * a[6] + b1.z, 0.f), o7 = fmaxf(d * a[7] + b1.w, 0.f);
        uint4 o;
        o.x = (unsigned)f2bf(o0) | ((unsigned)f2bf(o1) << 16);
        o.y = (unsigned)f2bf(o2) | ((unsigned)f2bf(o3) << 16);
        o.z = (unsigned)f2bf(o4) | ((unsigned)f2bf(o5) << 16);
        o.w = (unsigned)f2bf(o6) | ((unsigned)f2bf(o7) << 16);
        hout4[(long)node * 16 + ug] = o;
    }
}

// ---- K8: pooling + head ----
__global__ __launch_bounds__(128) void pool_head(const unsigned short* __restrict__ h,
                                                 const int* __restrict__ batch,
                                                 const float* __restrict__ Wlin,
                                                 const float* __restrict__ blin,
                                                 float* __restrict__ out) {
    __shared__ int bnd[2];
    int g = blockIdx.x;
    int c = threadIdx.x;
    if (c < 2) {
        int target = g + c;
        int lo = 0, hi = N_NODES;
        while (lo < hi) {
            int mid = (lo + hi) >> 1;
            if (batch[mid] < target) lo = mid + 1;
            else hi = mid;
        }
        bnd[c] = lo;
    }
    __syncthreads();
    int s = bnd[0], e = bnd[1];

    float sum = 0.f;
    for (int i = s; i < e; ++i) {
        union { unsigned u; float f; } v;
        v.u = (unsigned)h[(long)i * 128 + c] << 16;
        sum += v.f;
    }
    float inv = (e > s) ? 1.0f / (float)(e - s) : 1.0f;
    float m = sum * inv;

    __shared__ float red[128][2];
    red[c][0] = m * Wlin[c * 2 + 0];
    red[c][1] = m * Wlin[c * 2 + 1];
    __syncthreads();
#pragma unroll
    for (int off = 64; off > 0; off >>= 1) {
        if (c < off) {
            red[c][0] += red[c + off][0];
            red[c][1] += red[c + off][1];
        }
        __syncthreads();
    }
    if (c < 2) out[g * 2 + c] = red[0][c] + blin[c];
}

extern "C" void kernel_launch(void* const* d_in, const int* in_sizes, int n_in,
                              void* d_out, int out_size, void* d_ws, size_t ws_size,
                              hipStream_t stream) {
    const float* x    = (const float*)d_in[0];
    const int*   ei   = (const int*)d_in[1];
    const int*   batch= (const int*)d_in[2];
    const float* W1   = (const float*)d_in[4];
    const float* b1   = (const float*)d_in[5];
    const float* W2   = (const float*)d_in[6];
    const float* b2   = (const float*)d_in[7];
    const float* Wlin = (const float*)d_in[8];
    const float* blin = (const float*)d_in[9];
    float* out = (float*)d_out;

    const int* src = ei;
    const int* dst = ei + N_EDGES;

    char* ws = (char*)d_ws;
    const size_t KB = 1024;
    const size_t MB = 1048576;

    float* dinv     = (float*)(ws);
    int*   cnt      = (int*)  (ws + 256 * KB);
    int*   rowstart = (int*)  (ws + 512 * KB);
    int*   total    = (int*)  (ws + 768 * KB);          // 196 ints
    int*   bh       = (int*)  (ws + 832 * KB);          // 196*196 ints = 154 KB
    int*   goff     = (int*)  (ws + 1 * MB);            // 154 KB
    uint2* ebuf     = (uint2*)(ws + 2 * MB);            // 6.4 MB
    int*   esrc     = (int*)  (ws + 9 * MB);            // 3.2 MB
    unsigned short* W2f = (unsigned short*)(ws + 12 * MB + 576 * KB);  // 32 KB
    unsigned short* hp  = (unsigned short*)(ws + 13 * MB);   // N_PAD x 128 bf16
    unsigned short* h   = (unsigned short*)(ws + 26 * MB);   // N_PAD x 128 bf16

    const int NB_AG = (N_NODES + 3) / 4;          // 12500

    // K1: gemm1-raw || chunk hists || W2 prep
    k1_fused<<<NB_G + NBUCK + 8, 256, 0, stream>>>(dst, W1, W2, W2f, bh, x, hp);
    // K2: per-bucket parallel scan (replaces the serial 1-block scan_all)
    goff_scan<<<NBUCK, 256, 0, stream>>>(bh, goff, total);
    // K3/K4: scatter + sort (bstart derived in-block from total[])
    scatter_pairs<<<NBUCK, 256, 0, stream>>>(src, dst, goff, total, ebuf);
    bucket_sort<<<NBUCK, 256, 0, stream>>>(ebuf, total, rowstart, cnt, dinv, esrc);

    // K5: layer-1 aggregate with per-edge dinv (hp is raw)
    aggregate_w<<<NB_AG, 256, 0, stream>>>((const uint4*)hp, esrc, rowstart, cnt, dinv, b1, (uint4*)h);

    // K6/K7: layer 2
    gemm_mfma_bf16A<<<NB_G, 256, 0, stream>>>(h, W2f, dinv, hp);
    aggregate4<<<NB_AG, 256, 0, stream>>>((const uint4*)hp, esrc, rowstart, cnt, dinv, b2, (uint4*)h);

    // K8: pooling + head
    pool_head<<<N_GRAPHS, 128, 0, stream>>>(h, batch, Wlin, blin, out);
}